// Round 7
// baseline (2045.011 us; speedup 1.0000x reference)
//
#include <hip/hip_runtime.h>

typedef unsigned short u16;
typedef __attribute__((ext_vector_type(8))) short short8;
typedef __attribute__((ext_vector_type(4))) float f32x4;

#define N_NODES 40000
#define N_EDGES 640000

// ---------- bf16 helpers (RNE) ----------
__device__ __forceinline__ u16 f2bf(float f) {
  unsigned int u = __builtin_bit_cast(unsigned int, f);
  u += 0x7FFFu + ((u >> 16) & 1u);
  return (u16)(u >> 16);
}

// ---------- prep: W1/W2 f32 -> bf16, permuted into MFMA B-fragment order ----
// B frag for (ntile,ks): lane l holds B[k=ks*32+(l>>4)*8+j][n=ntile*16+(l&15)]
__global__ void prep_weights(const float* __restrict__ W1,
                             const float* __restrict__ W2,
                             u16* __restrict__ w1t, u16* __restrict__ w2t) {
  int gid = blockIdx.x * 256 + threadIdx.x;
  if (gid < 3 * 16 * 8 * 64) {            // W1: 3 layers x 16 ntiles x 8 ks x 64 lanes
    int l = gid >> 13;
    int rem = gid & 8191;
    int ntg = rem >> 9;
    int ks = (rem >> 6) & 7;
    int lane = rem & 63;
    int n = ntg * 16 + (lane & 15);
    int k0 = ks * 32 + (lane >> 4) * 8;
    const float* s = W1 + l * 65536 + n * 256 + k0;
    u16* d = w1t + (size_t)gid * 8;
#pragma unroll
    for (int j = 0; j < 8; ++j) d[j] = f2bf(s[j]);
  } else if (gid < 3 * 16 * 8 * 64 + 3 * 8 * 8 * 64) {  // W2: 8 ntiles
    int g = gid - 3 * 16 * 8 * 64;
    int l = g >> 12;
    int rem = g & 4095;
    int ntg = rem >> 9;
    int ks = (rem >> 6) & 7;
    int lane = rem & 63;
    int n = ntg * 16 + (lane & 15);
    int k0 = ks * 32 + (lane >> 4) * 8;
    const float* s = W2 + l * 32768 + n * 256 + k0;
    u16* d = w2t + (size_t)g * 8;
#pragma unroll
    for (int j = 0; j < 8; ++j) d[j] = f2bf(s[j]);
  }
}

// ---------- f32 -> bf16 (optional relu), vectorized x8 ----------
__global__ void cvt_vec(const float* __restrict__ in, u16* __restrict__ out,
                        int n8, int dorelu) {
  int i = blockIdx.x * 256 + threadIdx.x;
  if (i >= n8) return;
  const float4* p = reinterpret_cast<const float4*>(in) + (size_t)i * 2;
  float4 a = p[0], b = p[1];
  if (dorelu) {
    a.x = fmaxf(a.x, 0.f); a.y = fmaxf(a.y, 0.f);
    a.z = fmaxf(a.z, 0.f); a.w = fmaxf(a.w, 0.f);
    b.x = fmaxf(b.x, 0.f); b.y = fmaxf(b.y, 0.f);
    b.z = fmaxf(b.z, 0.f); b.w = fmaxf(b.w, 0.f);
  }
  short8 v;
  v[0] = (short)f2bf(a.x); v[1] = (short)f2bf(a.y);
  v[2] = (short)f2bf(a.z); v[3] = (short)f2bf(a.w);
  v[4] = (short)f2bf(b.x); v[5] = (short)f2bf(b.y);
  v[6] = (short)f2bf(b.z); v[7] = (short)f2bf(b.w);
  *reinterpret_cast<short8*>(out + (size_t)i * 8) = v;
}

// ---------- counting sort of edges by dst ----------
__global__ void hist_dst(const int* __restrict__ dst, int* __restrict__ cnt) {
  int e = blockIdx.x * 256 + threadIdx.x;
  if (e < N_EDGES) atomicAdd(&cnt[dst[e]], 1);
}

__global__ void scan_hist(const int* __restrict__ cnt, int* __restrict__ cursor) {
  __shared__ int ls[1024];
  const int tid = threadIdx.x;  // 1024 threads, 40 nodes each
  const int b = tid * 40;
  const int lim = (b < N_NODES) ? ((N_NODES - b < 40) ? (N_NODES - b) : 40) : 0;
  int s = 0;
  for (int j = 0; j < lim; ++j) s += cnt[b + j];
  ls[tid] = s;
  __syncthreads();
  for (int off = 1; off < 1024; off <<= 1) {
    int v = (tid >= off) ? ls[tid - off] : 0;
    __syncthreads();
    ls[tid] += v;
    __syncthreads();
  }
  int run = (tid == 0) ? 0 : ls[tid - 1];
  for (int j = 0; j < lim; ++j) {
    cursor[b + j] = run;
    run += cnt[b + j];
  }
}

__global__ void rank_edges(const int* __restrict__ src, const int* __restrict__ dst,
                           int* __restrict__ cursor, int* __restrict__ srcS,
                           int* __restrict__ dstS, int* __restrict__ rank) {
  int e = blockIdx.x * 256 + threadIdx.x;
  if (e >= N_EDGES) return;
  int d = dst[e];
  int r = atomicAdd(&cursor[d], 1);
  rank[e] = r;
  srcS[r] = src[e];
  dstS[r] = d;
}

// ---------- permute e into sorted slot order, f32 -> bf16 (raw, no relu) ----
__global__ void permute_e(const float* __restrict__ e, const int* __restrict__ rank,
                          u16* __restrict__ ebfS) {
  int t = blockIdx.x * 256 + threadIdx.x;
  int row = t >> 2;
  int part = t & 3;  // 32-float chunk of the row
  if (row >= N_EDGES) return;
  const float4* p = reinterpret_cast<const float4*>(e + (size_t)row * 128 + part * 32);
  u16* dp = ebfS + (size_t)rank[row] * 128 + part * 32;
#pragma unroll
  for (int j = 0; j < 4; ++j) {
    float4 a = p[j * 2], b = p[j * 2 + 1];
    short8 v;
    v[0] = (short)f2bf(a.x); v[1] = (short)f2bf(a.y);
    v[2] = (short)f2bf(a.z); v[3] = (short)f2bf(a.w);
    v[4] = (short)f2bf(b.x); v[5] = (short)f2bf(b.y);
    v[6] = (short)f2bf(b.z); v[7] = (short)f2bf(b.w);
    *(short8*)(dp + j * 8) = v;
  }
}

// ---------- in-place relu on packed bf16 (sign-mask trick) ----------
// NOTE (R7 fix): n4 is uint4 count. ebfS = 163,840,000 B = 10,240,000 uint4.
// R6 passed 20,480,000 -> 164MB overrun that corrupted weights/indices.
__global__ void relu_bf16_inplace(unsigned int* __restrict__ p, int n4) {
  int i = blockIdx.x * 256 + threadIdx.x;
  if (i >= n4) return;
  uint4 v = reinterpret_cast<uint4*>(p)[i];
#pragma unroll
  for (int j = 0; j < 4; ++j) {
    unsigned int u = (&v.x)[j];
    unsigned int t = (u >> 15) & 0x10001u;   // sign bits of both bf16 halves
    (&v.x)[j] = u & ~(t * 0xFFFFu);          // zero negative halves
  }
  reinterpret_cast<uint4*>(p)[i] = v;
}

// ---------- stats pass: x = concat(h,e)@W1^T, col sum/sumsq only, no x -----
// No LDS, no barrier. All large reads sequential bf16; h-gather L2/L3-hot.
__global__ __launch_bounds__(256) void gin_stats2(
    const u16* __restrict__ hbf, const u16* __restrict__ ebf,
    const int* __restrict__ srcS, const u16* __restrict__ w1t,
    float* __restrict__ stats) {
  const int tid = threadIdx.x;
  const long e0 = (long)blockIdx.x * 64;
  const int wid = tid >> 6, lane = tid & 63;
  const int lrow = lane & 15, lk = lane >> 4;
  int s4[4];
#pragma unroll
  for (int mt = 0; mt < 4; ++mt) s4[mt] = srcS[e0 + mt * 16 + lrow];
  f32x4 acc[4][4] = {};
  const u16* wbase = w1t + (size_t)wid * 16384;
  for (int ks = 0; ks < 8; ++ks) {
    short8 af[4];
#pragma unroll
    for (int mt = 0; mt < 4; ++mt) {
      const long row = e0 + mt * 16 + lrow;
      if (ks < 4)
        af[mt] = *(const short8*)(hbf + (size_t)s4[mt] * 128 + ks * 32 + lk * 8);
      else
        af[mt] = *(const short8*)(ebf + (size_t)row * 128 + (ks - 4) * 32 + lk * 8);
    }
#pragma unroll
    for (int nt = 0; nt < 4; ++nt) {
      short8 bf = *(const short8*)(wbase + ((nt * 8 + ks) * 64 + lane) * 8);
#pragma unroll
      for (int mt = 0; mt < 4; ++mt)
        acc[mt][nt] =
            __builtin_amdgcn_mfma_f32_16x16x32_bf16(af[mt], bf, acc[mt][nt], 0, 0, 0);
    }
  }
  float* statp = stats + (blockIdx.x & 63) * 512;
#pragma unroll
  for (int nt = 0; nt < 4; ++nt) {
    const int col = wid * 64 + nt * 16 + lrow;
    float sm = 0.f, sq = 0.f;
#pragma unroll
    for (int mt = 0; mt < 4; ++mt) {
#pragma unroll
      for (int i = 0; i < 4; ++i) {
        float v = acc[mt][nt][i];
        sm += v; sq += v * v;
      }
    }
    sm += __shfl_xor(sm, 16); sq += __shfl_xor(sq, 16);
    sm += __shfl_xor(sm, 32); sq += __shfl_xor(sq, 32);
    if (lk == 0) {
      atomicAdd(statp + col, sm);
      atomicAdd(statp + 256 + col, sq);
    }
  }
}

// ---------- BN finalize: a = gamma*rsqrt(var+eps), b = beta - mu*a ----------
__global__ void gin_bnstats(const float* __restrict__ stats,
                            const float* __restrict__ gamma,
                            const float* __restrict__ beta,
                            float* __restrict__ ab) {
  int c = threadIdx.x;  // 256 threads
  float sm = 0.f, sq = 0.f;
  for (int i = 0; i < 64; ++i) {
    sm += stats[i * 512 + c];
    sq += stats[i * 512 + 256 + c];
  }
  const float inv = 1.0f / (float)N_EDGES;
  float mu = sm * inv;
  float var = fmaxf(sq * inv - mu * mu, 0.f);
  float a = gamma[c] * rsqrtf(var + 1e-5f);
  ab[c] = a;
  ab[256 + c] = beta[c] - mu * a;
}

// ---------- fused: GEMM1 -> BN+relu -> LDS -> GEMM2 -> sorted scatter -------
// x never touches HBM.
__global__ __launch_bounds__(256) void gin_fused2(
    const u16* __restrict__ hbf, const u16* __restrict__ ebf,
    const int* __restrict__ srcS, const u16* __restrict__ w1t,
    const u16* __restrict__ w2t, const float* __restrict__ ab,
    const float* __restrict__ b2, const int* __restrict__ dstS,
    float* __restrict__ hnext) {
  __shared__ u16 sY[64][264];
  const int tid = threadIdx.x;
  const long e0 = (long)blockIdx.x * 64;
  const int wid = tid >> 6, lane = tid & 63;
  const int lrow = lane & 15, lk = lane >> 4;

  // ---- phase 1: GEMM1 (A-frags direct from global, proven R5 pattern)
  {
    int s4[4];
#pragma unroll
    for (int mt = 0; mt < 4; ++mt) s4[mt] = srcS[e0 + mt * 16 + lrow];
    float a4[4], c4[4];  // BN coeffs, loaded early
#pragma unroll
    for (int nt = 0; nt < 4; ++nt) {
      const int col = wid * 64 + nt * 16 + lrow;
      a4[nt] = ab[col];
      c4[nt] = ab[256 + col];
    }
    f32x4 acc[4][4] = {};
    const u16* wbase = w1t + (size_t)wid * 16384;
    for (int ks = 0; ks < 8; ++ks) {
      short8 af[4];
#pragma unroll
      for (int mt = 0; mt < 4; ++mt) {
        const long row = e0 + mt * 16 + lrow;
        if (ks < 4)
          af[mt] = *(const short8*)(hbf + (size_t)s4[mt] * 128 + ks * 32 + lk * 8);
        else
          af[mt] = *(const short8*)(ebf + (size_t)row * 128 + (ks - 4) * 32 + lk * 8);
      }
#pragma unroll
      for (int nt = 0; nt < 4; ++nt) {
        short8 bf = *(const short8*)(wbase + ((nt * 8 + ks) * 64 + lane) * 8);
#pragma unroll
        for (int mt = 0; mt < 4; ++mt)
          acc[mt][nt] =
              __builtin_amdgcn_mfma_f32_16x16x32_bf16(af[mt], bf, acc[mt][nt], 0, 0, 0);
      }
    }
    // ---- BN + relu in-register, y -> LDS (bf16); acc dies here
#pragma unroll
    for (int mt = 0; mt < 4; ++mt) {
#pragma unroll
      for (int nt = 0; nt < 4; ++nt) {
        const int col = wid * 64 + nt * 16 + lrow;
#pragma unroll
        for (int i = 0; i < 4; ++i) {
          float v = fmaxf(acc[mt][nt][i] * a4[nt] + c4[nt], 0.f);
          sY[mt * 16 + lk * 4 + i][col] = f2bf(v);
        }
      }
    }
  }
  __syncthreads();

  // ---- phase 2: GEMM2 from LDS y-tile (proven g2 structure)
  int nd[4][4];  // dst indices loaded now; latency hides under MFMA2
#pragma unroll
  for (int mt = 0; mt < 4; ++mt)
#pragma unroll
    for (int i = 0; i < 4; ++i) nd[mt][i] = dstS[e0 + mt * 16 + lk * 4 + i];
  float bb[2];
#pragma unroll
  for (int nt = 0; nt < 2; ++nt) bb[nt] = b2[wid * 32 + nt * 16 + lrow];

  f32x4 acc2[4][2] = {};
  const u16* wb2 = w2t + (size_t)wid * 8192;
  for (int ks = 0; ks < 8; ++ks) {
    short8 af[4];
#pragma unroll
    for (int mt = 0; mt < 4; ++mt)
      af[mt] = *(const short8*)&sY[mt * 16 + lrow][ks * 32 + lk * 8];
#pragma unroll
    for (int nt = 0; nt < 2; ++nt) {
      short8 bf = *(const short8*)(wb2 + ((nt * 8 + ks) * 64 + lane) * 8);
#pragma unroll
      for (int mt = 0; mt < 4; ++mt)
        acc2[mt][nt] =
            __builtin_amdgcn_mfma_f32_16x16x32_bf16(af[mt], bf, acc2[mt][nt], 0, 0, 0);
    }
  }

  // ---- epilogue: dst-sorted run compression, then atomicAdd per run
#pragma unroll
  for (int nt = 0; nt < 2; ++nt) {
    const int col = wid * 32 + nt * 16 + lrow;
    float carry = 0.f;
    int cur = nd[0][0];
#pragma unroll
    for (int mt = 0; mt < 4; ++mt) {
#pragma unroll
      for (int i = 0; i < 4; ++i) {
        int n_ = nd[mt][i];
        if (n_ != cur) {
          atomicAdd(hnext + (size_t)cur * 128 + col, carry);
          carry = 0.f;
          cur = n_;
        }
        carry += acc2[mt][nt][i] + bb[nt];
      }
    }
    atomicAdd(hnext + (size_t)cur * 128 + col, carry);
  }
}

// ---------- launch ----------
extern "C" void kernel_launch(void* const* d_in, const int* in_sizes, int n_in,
                              void* d_out, int out_size, void* d_ws, size_t ws_size,
                              hipStream_t stream) {
  const float* h     = (const float*)d_in[0];
  const float* e     = (const float*)d_in[1];
  const float* W1    = (const float*)d_in[2];
  // d_in[3] = b1: cancels exactly in BatchNorm -> unused
  const float* gamma = (const float*)d_in[4];
  const float* beta  = (const float*)d_in[5];
  const float* W2    = (const float*)d_in[6];
  const float* b2    = (const float*)d_in[7];
  const int* src     = (const int*)d_in[8];
  const int* dst     = (const int*)d_in[9];
  float* out = (float*)d_out;

  char* ws = (char*)d_ws;
  u16*   ebfS   = (u16*)(ws);                     // 163,840,000
  u16*   hbf    = (u16*)(ws + 163840000);         // 10,240,000
  float* h1     = (float*)(ws + 174080000);       // 20,480,000
  u16*   w1t    = (u16*)(ws + 194560000);         // 393,216
  u16*   w2t    = (u16*)(ws + 194953216);         // 196,608
  float* stats  = (float*)(ws + 195149824);       // 131,072
  float* ab     = (float*)(ws + 195280896);       // 2,048
  int*   cnt    = (int*)(ws + 195282944);         // 160,000
  int*   cursor = (int*)(ws + 195442944);         // 160,000
  int*   srcS   = (int*)(ws + 195602944);         // 2,560,000
  int*   dstS   = (int*)(ws + 198162944);         // 2,560,000
  int*   rank   = (int*)(ws + 200722944);         // 2,560,000 -> total 203,282,944

  prep_weights<<<144, 256, 0, stream>>>(W1, W2, w1t, w2t);
  cvt_vec<<<2500, 256, 0, stream>>>(h, hbf, 640000, 0);  // h -> bf16

  // counting sort of edges by dst (static across layers) + sorted bf16 e
  hipMemsetAsync(cnt, 0, 160000, stream);
  hist_dst<<<2500, 256, 0, stream>>>(dst, cnt);
  scan_hist<<<1, 1024, 0, stream>>>(cnt, cursor);
  rank_edges<<<2500, 256, 0, stream>>>(src, dst, cursor, srcS, dstS, rank);
  permute_e<<<10000, 256, 0, stream>>>(e, rank, ebfS);  // raw bf16, sorted order

  const int nblk = N_EDGES / 64;  // 10000
  for (int l = 0; l < 3; ++l) {
    hipMemsetAsync(stats, 0, 64 * 512 * 4, stream);
    gin_stats2<<<nblk, 256, 0, stream>>>(hbf, ebfS, srcS,
                                         w1t + (size_t)l * 65536, stats);
    gin_bnstats<<<1, 256, 0, stream>>>(stats, gamma + l * 256, beta + l * 256, ab);
    float* hnext = (l < 2) ? h1 : out;
    hipMemsetAsync(hnext, 0, (size_t)N_NODES * 128 * 4, stream);
    gin_fused2<<<nblk, 256, 0, stream>>>(hbf, ebfS, srcS,
                                         w1t + (size_t)l * 65536,
                                         w2t + (size_t)l * 32768, ab,
                                         b2 + l * 128, dstS, hnext);
    if (l == 0)  // e := relu(e) for layers 1,2 (in place, packed bf16)
      relu_bf16_inplace<<<40000, 256, 0, stream>>>((unsigned int*)ebfS, 10240000);
    if (l < 2) cvt_vec<<<2500, 256, 0, stream>>>(h1, hbf, 640000, 1);
  }
}

// Round 8
// 1901.477 us; speedup vs baseline: 1.0755x; 1.0755x over previous
//
#include <hip/hip_runtime.h>

typedef unsigned short u16;
typedef __attribute__((ext_vector_type(8))) short short8;
typedef __attribute__((ext_vector_type(4))) float f32x4;

#define N_NODES 40000
#define N_EDGES 640000

// ---------- bf16 helpers (RNE) ----------
__device__ __forceinline__ u16 f2bf(float f) {
  unsigned int u = __builtin_bit_cast(unsigned int, f);
  u += 0x7FFFu + ((u >> 16) & 1u);
  return (u16)(u >> 16);
}

// ---------- prep: W1/W2 f32 -> bf16, permuted into MFMA B-fragment order ----
// B frag for (ntile,ks): lane l holds B[k=ks*32+(l>>4)*8+j][n=ntile*16+(l&15)]
__global__ void prep_weights(const float* __restrict__ W1,
                             const float* __restrict__ W2,
                             u16* __restrict__ w1t, u16* __restrict__ w2t) {
  int gid = blockIdx.x * 256 + threadIdx.x;
  if (gid < 3 * 16 * 8 * 64) {            // W1: 3 layers x 16 ntiles x 8 ks x 64 lanes
    int l = gid >> 13;
    int rem = gid & 8191;
    int ntg = rem >> 9;
    int ks = (rem >> 6) & 7;
    int lane = rem & 63;
    int n = ntg * 16 + (lane & 15);
    int k0 = ks * 32 + (lane >> 4) * 8;
    const float* s = W1 + l * 65536 + n * 256 + k0;
    u16* d = w1t + (size_t)gid * 8;
#pragma unroll
    for (int j = 0; j < 8; ++j) d[j] = f2bf(s[j]);
  } else if (gid < 3 * 16 * 8 * 64 + 3 * 8 * 8 * 64) {  // W2: 8 ntiles
    int g = gid - 3 * 16 * 8 * 64;
    int l = g >> 12;
    int rem = g & 4095;
    int ntg = rem >> 9;
    int ks = (rem >> 6) & 7;
    int lane = rem & 63;
    int n = ntg * 16 + (lane & 15);
    int k0 = ks * 32 + (lane >> 4) * 8;
    const float* s = W2 + l * 32768 + n * 256 + k0;
    u16* d = w2t + (size_t)g * 8;
#pragma unroll
    for (int j = 0; j < 8; ++j) d[j] = f2bf(s[j]);
  }
}

// ---------- f32 -> bf16 (optional relu), vectorized x8 ----------
__global__ void cvt_vec(const float* __restrict__ in, u16* __restrict__ out,
                        int n8, int dorelu) {
  int i = blockIdx.x * 256 + threadIdx.x;
  if (i >= n8) return;
  const float4* p = reinterpret_cast<const float4*>(in) + (size_t)i * 2;
  float4 a = p[0], b = p[1];
  if (dorelu) {
    a.x = fmaxf(a.x, 0.f); a.y = fmaxf(a.y, 0.f);
    a.z = fmaxf(a.z, 0.f); a.w = fmaxf(a.w, 0.f);
    b.x = fmaxf(b.x, 0.f); b.y = fmaxf(b.y, 0.f);
    b.z = fmaxf(b.z, 0.f); b.w = fmaxf(b.w, 0.f);
  }
  short8 v;
  v[0] = (short)f2bf(a.x); v[1] = (short)f2bf(a.y);
  v[2] = (short)f2bf(a.z); v[3] = (short)f2bf(a.w);
  v[4] = (short)f2bf(b.x); v[5] = (short)f2bf(b.y);
  v[6] = (short)f2bf(b.z); v[7] = (short)f2bf(b.w);
  *reinterpret_cast<short8*>(out + (size_t)i * 8) = v;
}

// ---------- counting sort of edges by dst ----------
__global__ void hist_dst(const int* __restrict__ dst, int* __restrict__ cnt) {
  int e = blockIdx.x * 256 + threadIdx.x;
  if (e < N_EDGES) atomicAdd(&cnt[dst[e]], 1);
}

__global__ void scan_hist(const int* __restrict__ cnt, int* __restrict__ cursor) {
  __shared__ int ls[1024];
  const int tid = threadIdx.x;  // 1024 threads, 40 nodes each
  const int b = tid * 40;
  const int lim = (b < N_NODES) ? ((N_NODES - b < 40) ? (N_NODES - b) : 40) : 0;
  int s = 0;
  for (int j = 0; j < lim; ++j) s += cnt[b + j];
  ls[tid] = s;
  __syncthreads();
  for (int off = 1; off < 1024; off <<= 1) {
    int v = (tid >= off) ? ls[tid - off] : 0;
    __syncthreads();
    ls[tid] += v;
    __syncthreads();
  }
  int run = (tid == 0) ? 0 : ls[tid - 1];
  for (int j = 0; j < lim; ++j) {
    cursor[b + j] = run;
    run += cnt[b + j];
  }
}

__global__ void rank_edges(const int* __restrict__ src, const int* __restrict__ dst,
                           int* __restrict__ cursor, int* __restrict__ srcS,
                           int* __restrict__ dstS, int* __restrict__ rank) {
  int e = blockIdx.x * 256 + threadIdx.x;
  if (e >= N_EDGES) return;
  int d = dst[e];
  int r = atomicAdd(&cursor[d], 1);
  rank[e] = r;
  srcS[r] = src[e];
  dstS[r] = d;
}

// ---------- permute e into sorted slot order, f32 -> bf16 (raw, no relu) ----
__global__ void permute_e(const float* __restrict__ e, const int* __restrict__ rank,
                          u16* __restrict__ ebfS) {
  int t = blockIdx.x * 256 + threadIdx.x;
  int row = t >> 2;
  int part = t & 3;  // 32-float chunk of the row
  if (row >= N_EDGES) return;
  const float4* p = reinterpret_cast<const float4*>(e + (size_t)row * 128 + part * 32);
  u16* dp = ebfS + (size_t)rank[row] * 128 + part * 32;
#pragma unroll
  for (int j = 0; j < 4; ++j) {
    float4 a = p[j * 2], b = p[j * 2 + 1];
    short8 v;
    v[0] = (short)f2bf(a.x); v[1] = (short)f2bf(a.y);
    v[2] = (short)f2bf(a.z); v[3] = (short)f2bf(a.w);
    v[4] = (short)f2bf(b.x); v[5] = (short)f2bf(b.y);
    v[6] = (short)f2bf(b.z); v[7] = (short)f2bf(b.w);
    *(short8*)(dp + j * 8) = v;
  }
}

// ---------- in-place relu on packed bf16 (sign-mask trick) ----------
// n4 is uint4 count: ebfS = 163,840,000 B = 10,240,000 uint4 (R7 fix kept).
__global__ void relu_bf16_inplace(unsigned int* __restrict__ p, int n4) {
  int i = blockIdx.x * 256 + threadIdx.x;
  if (i >= n4) return;
  uint4 v = reinterpret_cast<uint4*>(p)[i];
#pragma unroll
  for (int j = 0; j < 4; ++j) {
    unsigned int u = (&v.x)[j];
    unsigned int t = (u >> 15) & 0x10001u;   // sign bits of both bf16 halves
    (&v.x)[j] = u & ~(t * 0xFFFFu);          // zero negative halves
  }
  reinterpret_cast<uint4*>(p)[i] = v;
}

// ---------- pipelined K-ladder building blocks (static indices, rule #20) ---
#define LOAD_AH(SET, KS) { _Pragma("unroll") \
  for (int mt = 0; mt < 4; ++mt) \
    SET[mt] = *(const short8*)(hbf + (size_t)s4[mt] * 128 + (KS) * 32 + lk * 8); }
#define LOAD_AE(SET, KS) { _Pragma("unroll") \
  for (int mt = 0; mt < 4; ++mt) \
    SET[mt] = *(const short8*)(ebf + (size_t)(e0 + mt * 16 + lrow) * 128 + ((KS) - 4) * 32 + lk * 8); }
#define LOAD_B4(SET, KS) { _Pragma("unroll") \
  for (int nt = 0; nt < 4; ++nt) \
    SET[nt] = *(const short8*)(wbase + ((nt * 8 + (KS)) * 64 + lane) * 8); }
#define LOAD_B2(SET, KS) { _Pragma("unroll") \
  for (int nt = 0; nt < 2; ++nt) \
    SET[nt] = *(const short8*)(wb2 + ((nt * 8 + (KS)) * 64 + lane) * 8); }
#define LOAD_AY(SET, KS) { _Pragma("unroll") \
  for (int mt = 0; mt < 4; ++mt) \
    SET[mt] = *(const short8*)&sY[mt * 16 + lrow][(KS) * 32 + lk * 8]; }
#define MFMA4(ACC, A, B) { _Pragma("unroll") \
  for (int nt = 0; nt < 4; ++nt) { _Pragma("unroll") \
    for (int mt = 0; mt < 4; ++mt) \
      ACC[mt][nt] = __builtin_amdgcn_mfma_f32_16x16x32_bf16(A[mt], B[nt], ACC[mt][nt], 0, 0, 0); } }
#define MFMA2(ACC, A, B) { _Pragma("unroll") \
  for (int nt = 0; nt < 2; ++nt) { _Pragma("unroll") \
    for (int mt = 0; mt < 4; ++mt) \
      ACC[mt][nt] = __builtin_amdgcn_mfma_f32_16x16x32_bf16(A[mt], B[nt], ACC[mt][nt], 0, 0, 0); } }

// Full 8-step ladder, depth-1 ping-pong: next set's loads are in flight while
// the current set feeds MFMAs -> compiler emits counted vmcnt, not drains.
#define K_LADDER_P1(ACC) \
  short8 a0[4], a1[4], b0[4], b1[4]; \
  LOAD_AH(a0, 0) LOAD_B4(b0, 0) \
  LOAD_AH(a1, 1) LOAD_B4(b1, 1) \
  MFMA4(ACC, a0, b0) \
  LOAD_AH(a0, 2) LOAD_B4(b0, 2) \
  MFMA4(ACC, a1, b1) \
  LOAD_AH(a1, 3) LOAD_B4(b1, 3) \
  MFMA4(ACC, a0, b0) \
  LOAD_AE(a0, 4) LOAD_B4(b0, 4) \
  MFMA4(ACC, a1, b1) \
  LOAD_AE(a1, 5) LOAD_B4(b1, 5) \
  MFMA4(ACC, a0, b0) \
  LOAD_AE(a0, 6) LOAD_B4(b0, 6) \
  MFMA4(ACC, a1, b1) \
  LOAD_AE(a1, 7) LOAD_B4(b1, 7) \
  MFMA4(ACC, a0, b0) \
  MFMA4(ACC, a1, b1)

// ---------- stats pass: x = concat(h,e)@W1^T, col sum/sumsq only, no x -----
__global__ __launch_bounds__(256) void gin_stats2(
    const u16* __restrict__ hbf, const u16* __restrict__ ebf,
    const int* __restrict__ srcS, const u16* __restrict__ w1t,
    float* __restrict__ stats) {
  const int tid = threadIdx.x;
  const long e0 = (long)blockIdx.x * 64;
  const int wid = tid >> 6, lane = tid & 63;
  const int lrow = lane & 15, lk = lane >> 4;
  int s4[4];
#pragma unroll
  for (int mt = 0; mt < 4; ++mt) s4[mt] = srcS[e0 + mt * 16 + lrow];
  f32x4 acc[4][4] = {};
  const u16* wbase = w1t + (size_t)wid * 16384;
  K_LADDER_P1(acc)
  float* statp = stats + (blockIdx.x & 63) * 512;
#pragma unroll
  for (int nt = 0; nt < 4; ++nt) {
    const int col = wid * 64 + nt * 16 + lrow;
    float sm = 0.f, sq = 0.f;
#pragma unroll
    for (int mt = 0; mt < 4; ++mt) {
#pragma unroll
      for (int i = 0; i < 4; ++i) {
        float v = acc[mt][nt][i];
        sm += v; sq += v * v;
      }
    }
    sm += __shfl_xor(sm, 16); sq += __shfl_xor(sq, 16);
    sm += __shfl_xor(sm, 32); sq += __shfl_xor(sq, 32);
    if (lk == 0) {
      atomicAdd(statp + col, sm);
      atomicAdd(statp + 256 + col, sq);
    }
  }
}

// ---------- BN finalize: a = gamma*rsqrt(var+eps), b = beta - mu*a ----------
__global__ void gin_bnstats(const float* __restrict__ stats,
                            const float* __restrict__ gamma,
                            const float* __restrict__ beta,
                            float* __restrict__ ab) {
  int c = threadIdx.x;  // 256 threads
  float sm = 0.f, sq = 0.f;
  for (int i = 0; i < 64; ++i) {
    sm += stats[i * 512 + c];
    sq += stats[i * 512 + 256 + c];
  }
  const float inv = 1.0f / (float)N_EDGES;
  float mu = sm * inv;
  float var = fmaxf(sq * inv - mu * mu, 0.f);
  float a = gamma[c] * rsqrtf(var + 1e-5f);
  ab[c] = a;
  ab[256 + c] = beta[c] - mu * a;
}

// ---------- fused: GEMM1 -> BN+relu -> LDS -> GEMM2 -> sorted scatter -------
// x never touches HBM. Both K-loops pipelined (R8).
__global__ __launch_bounds__(256) void gin_fused2(
    const u16* __restrict__ hbf, const u16* __restrict__ ebf,
    const int* __restrict__ srcS, const u16* __restrict__ w1t,
    const u16* __restrict__ w2t, const float* __restrict__ ab,
    const float* __restrict__ b2, const int* __restrict__ dstS,
    float* __restrict__ hnext) {
  __shared__ u16 sY[64][264];
  const int tid = threadIdx.x;
  const long e0 = (long)blockIdx.x * 64;
  const int wid = tid >> 6, lane = tid & 63;
  const int lrow = lane & 15, lk = lane >> 4;

  // ---- phase 1: GEMM1 (pipelined ladder)
  {
    int s4[4];
#pragma unroll
    for (int mt = 0; mt < 4; ++mt) s4[mt] = srcS[e0 + mt * 16 + lrow];
    float a4[4], c4[4];  // BN coeffs, loaded early
#pragma unroll
    for (int nt = 0; nt < 4; ++nt) {
      const int col = wid * 64 + nt * 16 + lrow;
      a4[nt] = ab[col];
      c4[nt] = ab[256 + col];
    }
    f32x4 acc[4][4] = {};
    const u16* wbase = w1t + (size_t)wid * 16384;
    K_LADDER_P1(acc)
    // ---- BN + relu in-register, y -> LDS (bf16); acc dies here
#pragma unroll
    for (int mt = 0; mt < 4; ++mt) {
#pragma unroll
      for (int nt = 0; nt < 4; ++nt) {
        const int col = wid * 64 + nt * 16 + lrow;
#pragma unroll
        for (int i = 0; i < 4; ++i) {
          float v = fmaxf(acc[mt][nt][i] * a4[nt] + c4[nt], 0.f);
          sY[mt * 16 + lk * 4 + i][col] = f2bf(v);
        }
      }
    }
  }
  __syncthreads();

  // ---- phase 2: GEMM2 from LDS y-tile (pipelined: ds_read y || global w2t)
  int nd[4][4];  // dst indices loaded now; latency hides under MFMA2
#pragma unroll
  for (int mt = 0; mt < 4; ++mt)
#pragma unroll
    for (int i = 0; i < 4; ++i) nd[mt][i] = dstS[e0 + mt * 16 + lk * 4 + i];
  float bb[2];
#pragma unroll
  for (int nt = 0; nt < 2; ++nt) bb[nt] = b2[wid * 32 + nt * 16 + lrow];

  f32x4 acc2[4][2] = {};
  const u16* wb2 = w2t + (size_t)wid * 8192;
  {
    short8 y0[4], y1[4], c0[2], c1[2];
    LOAD_AY(y0, 0) LOAD_B2(c0, 0)
    LOAD_AY(y1, 1) LOAD_B2(c1, 1)
    MFMA2(acc2, y0, c0)
    LOAD_AY(y0, 2) LOAD_B2(c0, 2)
    MFMA2(acc2, y1, c1)
    LOAD_AY(y1, 3) LOAD_B2(c1, 3)
    MFMA2(acc2, y0, c0)
    LOAD_AY(y0, 4) LOAD_B2(c0, 4)
    MFMA2(acc2, y1, c1)
    LOAD_AY(y1, 5) LOAD_B2(c1, 5)
    MFMA2(acc2, y0, c0)
    LOAD_AY(y0, 6) LOAD_B2(c0, 6)
    MFMA2(acc2, y1, c1)
    LOAD_AY(y1, 7) LOAD_B2(c1, 7)
    MFMA2(acc2, y0, c0)
    MFMA2(acc2, y1, c1)
  }

  // ---- epilogue: dst-sorted run compression, then atomicAdd per run
#pragma unroll
  for (int nt = 0; nt < 2; ++nt) {
    const int col = wid * 32 + nt * 16 + lrow;
    float carry = 0.f;
    int cur = nd[0][0];
#pragma unroll
    for (int mt = 0; mt < 4; ++mt) {
#pragma unroll
      for (int i = 0; i < 4; ++i) {
        int n_ = nd[mt][i];
        if (n_ != cur) {
          atomicAdd(hnext + (size_t)cur * 128 + col, carry);
          carry = 0.f;
          cur = n_;
        }
        carry += acc2[mt][nt][i] + bb[nt];
      }
    }
    atomicAdd(hnext + (size_t)cur * 128 + col, carry);
  }
}

// ---------- launch ----------
extern "C" void kernel_launch(void* const* d_in, const int* in_sizes, int n_in,
                              void* d_out, int out_size, void* d_ws, size_t ws_size,
                              hipStream_t stream) {
  const float* h     = (const float*)d_in[0];
  const float* e     = (const float*)d_in[1];
  const float* W1    = (const float*)d_in[2];
  // d_in[3] = b1: cancels exactly in BatchNorm -> unused
  const float* gamma = (const float*)d_in[4];
  const float* beta  = (const float*)d_in[5];
  const float* W2    = (const float*)d_in[6];
  const float* b2    = (const float*)d_in[7];
  const int* src     = (const int*)d_in[8];
  const int* dst     = (const int*)d_in[9];
  float* out = (float*)d_out;

  char* ws = (char*)d_ws;
  u16*   ebfS   = (u16*)(ws);                     // 163,840,000
  u16*   hbf    = (u16*)(ws + 163840000);         // 10,240,000
  float* h1     = (float*)(ws + 174080000);       // 20,480,000
  u16*   w1t    = (u16*)(ws + 194560000);         // 393,216
  u16*   w2t    = (u16*)(ws + 194953216);         // 196,608
  float* stats  = (float*)(ws + 195149824);       // 131,072
  float* ab     = (float*)(ws + 195280896);       // 2,048
  int*   cnt    = (int*)(ws + 195282944);         // 160,000
  int*   cursor = (int*)(ws + 195442944);         // 160,000
  int*   srcS   = (int*)(ws + 195602944);         // 2,560,000
  int*   dstS   = (int*)(ws + 198162944);         // 2,560,000
  int*   rank   = (int*)(ws + 200722944);         // 2,560,000 -> total 203,282,944

  prep_weights<<<144, 256, 0, stream>>>(W1, W2, w1t, w2t);
  cvt_vec<<<2500, 256, 0, stream>>>(h, hbf, 640000, 0);  // h -> bf16

  // counting sort of edges by dst (static across layers) + sorted bf16 e
  hipMemsetAsync(cnt, 0, 160000, stream);
  hist_dst<<<2500, 256, 0, stream>>>(dst, cnt);
  scan_hist<<<1, 1024, 0, stream>>>(cnt, cursor);
  rank_edges<<<2500, 256, 0, stream>>>(src, dst, cursor, srcS, dstS, rank);
  permute_e<<<10000, 256, 0, stream>>>(e, rank, ebfS);  // raw bf16, sorted order

  const int nblk = N_EDGES / 64;  // 10000
  for (int l = 0; l < 3; ++l) {
    hipMemsetAsync(stats, 0, 64 * 512 * 4, stream);
    gin_stats2<<<nblk, 256, 0, stream>>>(hbf, ebfS, srcS,
                                         w1t + (size_t)l * 65536, stats);
    gin_bnstats<<<1, 256, 0, stream>>>(stats, gamma + l * 256, beta + l * 256, ab);
    float* hnext = (l < 2) ? h1 : out;
    hipMemsetAsync(hnext, 0, (size_t)N_NODES * 128 * 4, stream);
    gin_fused2<<<nblk, 256, 0, stream>>>(hbf, ebfS, srcS,
                                         w1t + (size_t)l * 65536,
                                         w2t + (size_t)l * 32768, ab,
                                         b2 + l * 128, dstS, hnext);
    if (l == 0)  // e := relu(e) for layers 1,2 (in place, packed bf16)
      relu_bf16_inplace<<<40000, 256, 0, stream>>>((unsigned int*)ebfS, 10240000);
    if (l < 2) cvt_vec<<<2500, 256, 0, stream>>>(h1, hbf, 640000, 1);
  }
}

// Round 9
// 1448.448 us; speedup vs baseline: 1.4119x; 1.3128x over previous
//
#include <hip/hip_runtime.h>

typedef unsigned short u16;
typedef __attribute__((ext_vector_type(8))) short short8;
typedef __attribute__((ext_vector_type(4))) float f32x4;

#define N_NODES 40000
#define N_EDGES 640000

// ---------- bf16 helpers (RNE) ----------
__device__ __forceinline__ u16 f2bf(float f) {
  unsigned int u = __builtin_bit_cast(unsigned int, f);
  u += 0x7FFFu + ((u >> 16) & 1u);
  return (u16)(u >> 16);
}
__device__ __forceinline__ float bf2f(u16 h) {
  unsigned int u = ((unsigned int)h) << 16;
  return __builtin_bit_cast(float, u);
}

// ---------- prep: W1/W2 f32 -> bf16, permuted into MFMA B-fragment order ----
// B frag for (ntile,ks): lane l holds B[k=ks*32+(l>>4)*8+j][n=ntile*16+(l&15)]
__global__ void prep_weights(const float* __restrict__ W1,
                             const float* __restrict__ W2,
                             u16* __restrict__ w1t, u16* __restrict__ w2t) {
  int gid = blockIdx.x * 256 + threadIdx.x;
  if (gid < 3 * 16 * 8 * 64) {            // W1: 3 layers x 16 ntiles x 8 ks x 64 lanes
    int l = gid >> 13;
    int rem = gid & 8191;
    int ntg = rem >> 9;
    int ks = (rem >> 6) & 7;
    int lane = rem & 63;
    int n = ntg * 16 + (lane & 15);
    int k0 = ks * 32 + (lane >> 4) * 8;
    const float* s = W1 + l * 65536 + n * 256 + k0;
    u16* d = w1t + (size_t)gid * 8;
#pragma unroll
    for (int j = 0; j < 8; ++j) d[j] = f2bf(s[j]);
  } else if (gid < 3 * 16 * 8 * 64 + 3 * 8 * 8 * 64) {  // W2: 8 ntiles
    int g = gid - 3 * 16 * 8 * 64;
    int l = g >> 12;
    int rem = g & 4095;
    int ntg = rem >> 9;
    int ks = (rem >> 6) & 7;
    int lane = rem & 63;
    int n = ntg * 16 + (lane & 15);
    int k0 = ks * 32 + (lane >> 4) * 8;
    const float* s = W2 + l * 32768 + n * 256 + k0;
    u16* d = w2t + (size_t)g * 8;
#pragma unroll
    for (int j = 0; j < 8; ++j) d[j] = f2bf(s[j]);
  }
}

// ---------- f32 -> bf16 (optional relu), vectorized x8 ----------
__global__ void cvt_vec(const float* __restrict__ in, u16* __restrict__ out,
                        int n8, int dorelu) {
  int i = blockIdx.x * 256 + threadIdx.x;
  if (i >= n8) return;
  const float4* p = reinterpret_cast<const float4*>(in) + (size_t)i * 2;
  float4 a = p[0], b = p[1];
  if (dorelu) {
    a.x = fmaxf(a.x, 0.f); a.y = fmaxf(a.y, 0.f);
    a.z = fmaxf(a.z, 0.f); a.w = fmaxf(a.w, 0.f);
    b.x = fmaxf(b.x, 0.f); b.y = fmaxf(b.y, 0.f);
    b.z = fmaxf(b.z, 0.f); b.w = fmaxf(b.w, 0.f);
  }
  short8 v;
  v[0] = (short)f2bf(a.x); v[1] = (short)f2bf(a.y);
  v[2] = (short)f2bf(a.z); v[3] = (short)f2bf(a.w);
  v[4] = (short)f2bf(b.x); v[5] = (short)f2bf(b.y);
  v[6] = (short)f2bf(b.z); v[7] = (short)f2bf(b.w);
  *reinterpret_cast<short8*>(out + (size_t)i * 8) = v;
}

// ---------- counting sort of edges by dst ----------
__global__ void hist_dst(const int* __restrict__ dst, int* __restrict__ cnt) {
  int e = blockIdx.x * 256 + threadIdx.x;
  if (e < N_EDGES) atomicAdd(&cnt[dst[e]], 1);
}

__global__ void scan_hist(const int* __restrict__ cnt, int* __restrict__ cursor) {
  __shared__ int ls[1024];
  const int tid = threadIdx.x;  // 1024 threads, 40 nodes each
  const int b = tid * 40;
  const int lim = (b < N_NODES) ? ((N_NODES - b < 40) ? (N_NODES - b) : 40) : 0;
  int s = 0;
  for (int j = 0; j < lim; ++j) s += cnt[b + j];
  ls[tid] = s;
  __syncthreads();
  for (int off = 1; off < 1024; off <<= 1) {
    int v = (tid >= off) ? ls[tid - off] : 0;
    __syncthreads();
    ls[tid] += v;
    __syncthreads();
  }
  int run = (tid == 0) ? 0 : ls[tid - 1];
  for (int j = 0; j < lim; ++j) {
    cursor[b + j] = run;
    run += cnt[b + j];
  }
}

__global__ void rank_edges(const int* __restrict__ src, const int* __restrict__ dst,
                           int* __restrict__ cursor, int* __restrict__ srcS,
                           int* __restrict__ dstS, int* __restrict__ rank) {
  int e = blockIdx.x * 256 + threadIdx.x;
  if (e >= N_EDGES) return;
  int d = dst[e];
  int r = atomicAdd(&cursor[d], 1);
  rank[e] = r;
  srcS[r] = src[e];
  dstS[r] = d;
}

// ---------- permute e into sorted slot order, f32 -> bf16 (raw, no relu) ----
__global__ void permute_e(const float* __restrict__ e, const int* __restrict__ rank,
                          u16* __restrict__ ebfS) {
  int t = blockIdx.x * 256 + threadIdx.x;
  int row = t >> 2;
  int part = t & 3;  // 32-float chunk of the row
  if (row >= N_EDGES) return;
  const float4* p = reinterpret_cast<const float4*>(e + (size_t)row * 128 + part * 32);
  u16* dp = ebfS + (size_t)rank[row] * 128 + part * 32;
#pragma unroll
  for (int j = 0; j < 4; ++j) {
    float4 a = p[j * 2], b = p[j * 2 + 1];
    short8 v;
    v[0] = (short)f2bf(a.x); v[1] = (short)f2bf(a.y);
    v[2] = (short)f2bf(a.z); v[3] = (short)f2bf(a.w);
    v[4] = (short)f2bf(b.x); v[5] = (short)f2bf(b.y);
    v[6] = (short)f2bf(b.z); v[7] = (short)f2bf(b.w);
    *(short8*)(dp + j * 8) = v;
  }
}

// ---------- in-place relu on packed bf16 (sign-mask trick) ----------
// n4 is uint4 count: ebfS = 163,840,000 B = 10,240,000 uint4.
__global__ void relu_bf16_inplace(unsigned int* __restrict__ p, int n4) {
  int i = blockIdx.x * 256 + threadIdx.x;
  if (i >= n4) return;
  uint4 v = reinterpret_cast<uint4*>(p)[i];
#pragma unroll
  for (int j = 0; j < 4; ++j) {
    unsigned int u = (&v.x)[j];
    unsigned int t = (u >> 15) & 0x10001u;   // sign bits of both bf16 halves
    (&v.x)[j] = u & ~(t * 0xFFFFu);          // zero negative halves
  }
  reinterpret_cast<uint4*>(p)[i] = v;
}

// ---------- ladder building blocks ----------
#define LOAD_B4(SET, KS) { _Pragma("unroll") \
  for (int nt = 0; nt < 4; ++nt) \
    SET[nt] = *(const short8*)(wbase + ((nt * 8 + (KS)) * 64 + lane) * 8); }
#define LOAD_B2(SET, KS) { _Pragma("unroll") \
  for (int nt = 0; nt < 2; ++nt) \
    SET[nt] = *(const short8*)(wb2 + ((nt * 8 + (KS)) * 64 + lane) * 8); }
#define LOAD_A_LDS(ARR, SET, KS) { _Pragma("unroll") \
  for (int mt = 0; mt < 4; ++mt) \
    SET[mt] = *(const short8*)&ARR[(KS)][mt * 16 + lrow][lk * 8]; }
#define MFMA4(ACC, A, B) { _Pragma("unroll") \
  for (int nt = 0; nt < 4; ++nt) { _Pragma("unroll") \
    for (int mt = 0; mt < 4; ++mt) \
      ACC[mt][nt] = __builtin_amdgcn_mfma_f32_16x16x32_bf16(A[mt], B[nt], ACC[mt][nt], 0, 0, 0); } }
#define MFMA2(ACC, A, B) { _Pragma("unroll") \
  for (int nt = 0; nt < 2; ++nt) { _Pragma("unroll") \
    for (int mt = 0; mt < 4; ++mt) \
      ACC[mt][nt] = __builtin_amdgcn_mfma_f32_16x16x32_bf16(A[mt], B[nt], ACC[mt][nt], 0, 0, 0); } }

// ---------- g1: x = concat(h[srcS], e)@W1^T ; x-write + col stats ----------
// A-tile staged depth-8: each thread issues its 8 independent global loads
// upfront (h L3-gather + e HBM-stream), ds_writes into ks-major padded LDS.
// K-ladder then reads A from LDS (fast) and only B (L2-hot) from global.
__global__ __launch_bounds__(256) void gin_g1(
    const u16* __restrict__ hbf, const u16* __restrict__ ebf,
    const int* __restrict__ srcS, const u16* __restrict__ w1t,
    u16* __restrict__ xout, float* __restrict__ stats) {
  __shared__ u16 sA[8][64][36];  // 36,864 B; 72B row stride -> ~2-way banks
  const int tid = threadIdx.x;
  const long e0 = (long)blockIdx.x * 64;
  const int wid = tid >> 6, lane = tid & 63;
  const int lrow = lane & 15, lk = lane >> 4;

  // ---- stage: thread -> (row = tid>>2, chunk c2 = tid&3), one chunk per ks
  {
    const int row = tid >> 2, c2 = tid & 3;
    const int sr = srcS[e0 + row];
    const u16* hrow = hbf + (size_t)sr * 128 + c2 * 8;
    const u16* erow = ebf + (size_t)(e0 + row) * 128 + c2 * 8;
    short8 t0 = *(const short8*)(hrow + 0);
    short8 t1 = *(const short8*)(hrow + 32);
    short8 t2 = *(const short8*)(hrow + 64);
    short8 t3 = *(const short8*)(hrow + 96);
    short8 t4 = *(const short8*)(erow + 0);
    short8 t5 = *(const short8*)(erow + 32);
    short8 t6 = *(const short8*)(erow + 64);
    short8 t7 = *(const short8*)(erow + 96);
    *(short8*)&sA[0][row][c2 * 8] = t0;
    *(short8*)&sA[1][row][c2 * 8] = t1;
    *(short8*)&sA[2][row][c2 * 8] = t2;
    *(short8*)&sA[3][row][c2 * 8] = t3;
    *(short8*)&sA[4][row][c2 * 8] = t4;
    *(short8*)&sA[5][row][c2 * 8] = t5;
    *(short8*)&sA[6][row][c2 * 8] = t6;
    *(short8*)&sA[7][row][c2 * 8] = t7;
  }
  __syncthreads();

  // ---- K-ladder: A from LDS, B ping-pong from L2
  f32x4 acc[4][4] = {};
  const u16* wbase = w1t + (size_t)wid * 16384;
  {
    short8 a0[4], a1[4], b0[4], b1[4];
    LOAD_A_LDS(sA, a0, 0) LOAD_B4(b0, 0)
    LOAD_A_LDS(sA, a1, 1) LOAD_B4(b1, 1)
    MFMA4(acc, a0, b0)
    LOAD_A_LDS(sA, a0, 2) LOAD_B4(b0, 2)
    MFMA4(acc, a1, b1)
    LOAD_A_LDS(sA, a1, 3) LOAD_B4(b1, 3)
    MFMA4(acc, a0, b0)
    LOAD_A_LDS(sA, a0, 4) LOAD_B4(b0, 4)
    MFMA4(acc, a1, b1)
    LOAD_A_LDS(sA, a1, 5) LOAD_B4(b1, 5)
    MFMA4(acc, a0, b0)
    LOAD_A_LDS(sA, a0, 6) LOAD_B4(b0, 6)
    MFMA4(acc, a1, b1)
    LOAD_A_LDS(sA, a1, 7) LOAD_B4(b1, 7)
    MFMA4(acc, a0, b0)
    MFMA4(acc, a1, b1)
  }

  // ---- epilogue: direct x stores (R3-proven) + col sum/sumsq partials
  float* statp = stats + (blockIdx.x & 63) * 512;
#pragma unroll
  for (int nt = 0; nt < 4; ++nt) {
    const int col = wid * 64 + nt * 16 + lrow;
    float sm = 0.f, sq = 0.f;
#pragma unroll
    for (int mt = 0; mt < 4; ++mt) {
#pragma unroll
      for (int i = 0; i < 4; ++i) {
        float v = acc[mt][nt][i];
        const long row = e0 + mt * 16 + lk * 4 + i;
        xout[(size_t)row * 256 + col] = f2bf(v);
        sm += v; sq += v * v;
      }
    }
    sm += __shfl_xor(sm, 16); sq += __shfl_xor(sq, 16);
    sm += __shfl_xor(sm, 32); sq += __shfl_xor(sq, 32);
    if (lk == 0) {
      atomicAdd(statp + col, sm);
      atomicAdd(statp + 256 + col, sq);
    }
  }
}

// ---------- BN finalize: a = gamma*rsqrt(var+eps), b = beta - mu*a ----------
__global__ void gin_bnstats(const float* __restrict__ stats,
                            const float* __restrict__ gamma,
                            const float* __restrict__ beta,
                            float* __restrict__ ab) {
  int c = threadIdx.x;  // 256 threads
  float sm = 0.f, sq = 0.f;
  for (int i = 0; i < 64; ++i) {
    sm += stats[i * 512 + c];
    sq += stats[i * 512 + 256 + c];
  }
  const float inv = 1.0f / (float)N_EDGES;
  float mu = sm * inv;
  float var = fmaxf(sq * inv - mu * mu, 0.f);
  float a = gamma[c] * rsqrtf(var + 1e-5f);
  ab[c] = a;
  ab[256 + c] = beta[c] - mu * a;
}

// ---------- normalize one staged x chunk: bf16 -> relu(a*x+b) -> bf16 -------
__device__ __forceinline__ short8 normchunk(short8 u, const float* __restrict__ ab,
                                            int k0) {
  float4 a0 = *(const float4*)(ab + k0);
  float4 a1 = *(const float4*)(ab + k0 + 4);
  float4 b0 = *(const float4*)(ab + 256 + k0);
  float4 b1 = *(const float4*)(ab + 256 + k0 + 4);
  short8 v;
#pragma unroll
  for (int j = 0; j < 4; ++j) {
    float f = fmaxf(bf2f((u16)u[j]) * (&a0.x)[j] + (&b0.x)[j], 0.f);
    v[j] = (short)f2bf(f);
  }
#pragma unroll
  for (int j = 0; j < 4; ++j) {
    float f = fmaxf(bf2f((u16)u[4 + j]) * (&a1.x)[j] + (&b1.x)[j], 0.f);
    v[4 + j] = (short)f2bf(f);
  }
  return v;
}

// ---------- g2: m = relu(x*a+b)@W2^T ; run-compressed scatter to dstS -------
// x-tile staged depth-8 (8 independent loads/thread), BN+relu in-register
// before ds_write; ladder reads A from LDS, B2 ping-pong from L2.
__global__ __launch_bounds__(256) void gin_g2(
    const u16* __restrict__ xin, const u16* __restrict__ w2t,
    const float* __restrict__ ab, const float* __restrict__ b2,
    const int* __restrict__ dstS, float* __restrict__ hnext) {
  __shared__ u16 sX[8][64][36];
  const int tid = threadIdx.x;
  const long e0 = (long)blockIdx.x * 64;
  const int wid = tid >> 6, lane = tid & 63;
  const int lrow = lane & 15, lk = lane >> 4;

  // ---- stage: 8 independent x loads, normalize, ds_write
  {
    const int row = tid >> 2, c2 = tid & 3;
    const u16* xrow = xin + (size_t)(e0 + row) * 256 + c2 * 8;
    short8 t0 = *(const short8*)(xrow + 0);
    short8 t1 = *(const short8*)(xrow + 32);
    short8 t2 = *(const short8*)(xrow + 64);
    short8 t3 = *(const short8*)(xrow + 96);
    short8 t4 = *(const short8*)(xrow + 128);
    short8 t5 = *(const short8*)(xrow + 160);
    short8 t6 = *(const short8*)(xrow + 192);
    short8 t7 = *(const short8*)(xrow + 224);
    const int kc = c2 * 8;
    *(short8*)&sX[0][row][c2 * 8] = normchunk(t0, ab, 0 + kc);
    *(short8*)&sX[1][row][c2 * 8] = normchunk(t1, ab, 32 + kc);
    *(short8*)&sX[2][row][c2 * 8] = normchunk(t2, ab, 64 + kc);
    *(short8*)&sX[3][row][c2 * 8] = normchunk(t3, ab, 96 + kc);
    *(short8*)&sX[4][row][c2 * 8] = normchunk(t4, ab, 128 + kc);
    *(short8*)&sX[5][row][c2 * 8] = normchunk(t5, ab, 160 + kc);
    *(short8*)&sX[6][row][c2 * 8] = normchunk(t6, ab, 192 + kc);
    *(short8*)&sX[7][row][c2 * 8] = normchunk(t7, ab, 224 + kc);
  }
  __syncthreads();

  // ---- K-ladder
  int nd[4][4];
#pragma unroll
  for (int mt = 0; mt < 4; ++mt)
#pragma unroll
    for (int i = 0; i < 4; ++i) nd[mt][i] = dstS[e0 + mt * 16 + lk * 4 + i];
  float bb[2];
#pragma unroll
  for (int nt = 0; nt < 2; ++nt) bb[nt] = b2[wid * 32 + nt * 16 + lrow];

  f32x4 acc2[4][2] = {};
  const u16* wb2 = w2t + (size_t)wid * 8192;
  {
    short8 y0[4], y1[4], c0[2], c1[2];
    LOAD_A_LDS(sX, y0, 0) LOAD_B2(c0, 0)
    LOAD_A_LDS(sX, y1, 1) LOAD_B2(c1, 1)
    MFMA2(acc2, y0, c0)
    LOAD_A_LDS(sX, y0, 2) LOAD_B2(c0, 2)
    MFMA2(acc2, y1, c1)
    LOAD_A_LDS(sX, y1, 3) LOAD_B2(c1, 3)
    MFMA2(acc2, y0, c0)
    LOAD_A_LDS(sX, y0, 4) LOAD_B2(c0, 4)
    MFMA2(acc2, y1, c1)
    LOAD_A_LDS(sX, y1, 5) LOAD_B2(c1, 5)
    MFMA2(acc2, y0, c0)
    LOAD_A_LDS(sX, y0, 6) LOAD_B2(c0, 6)
    MFMA2(acc2, y1, c1)
    LOAD_A_LDS(sX, y1, 7) LOAD_B2(c1, 7)
    MFMA2(acc2, y0, c0)
    MFMA2(acc2, y1, c1)
  }

  // ---- epilogue: dst-sorted run compression, then atomicAdd per run
#pragma unroll
  for (int nt = 0; nt < 2; ++nt) {
    const int col = wid * 32 + nt * 16 + lrow;
    float carry = 0.f;
    int cur = nd[0][0];
#pragma unroll
    for (int mt = 0; mt < 4; ++mt) {
#pragma unroll
      for (int i = 0; i < 4; ++i) {
        int n_ = nd[mt][i];
        if (n_ != cur) {
          atomicAdd(hnext + (size_t)cur * 128 + col, carry);
          carry = 0.f;
          cur = n_;
        }
        carry += acc2[mt][nt][i] + bb[nt];
      }
    }
    atomicAdd(hnext + (size_t)cur * 128 + col, carry);
  }
}

// ---------- launch ----------
extern "C" void kernel_launch(void* const* d_in, const int* in_sizes, int n_in,
                              void* d_out, int out_size, void* d_ws, size_t ws_size,
                              hipStream_t stream) {
  const float* h     = (const float*)d_in[0];
  const float* e     = (const float*)d_in[1];
  const float* W1    = (const float*)d_in[2];
  // d_in[3] = b1: cancels exactly in BatchNorm -> unused
  const float* gamma = (const float*)d_in[4];
  const float* beta  = (const float*)d_in[5];
  const float* W2    = (const float*)d_in[6];
  const float* b2    = (const float*)d_in[7];
  const int* src     = (const int*)d_in[8];
  const int* dst     = (const int*)d_in[9];
  float* out = (float*)d_out;

  char* ws = (char*)d_ws;
  u16*   xbuf   = (u16*)(ws);                     // 327,680,000
  u16*   ebfS   = (u16*)(ws + 327680000);         // 163,840,000
  u16*   hbf    = (u16*)(ws + 491520000);         // 10,240,000
  float* h1     = (float*)(ws + 501760000);       // 20,480,000
  u16*   w1t    = (u16*)(ws + 522240000);         // 393,216
  u16*   w2t    = (u16*)(ws + 522633216);         // 196,608
  float* stats  = (float*)(ws + 522829824);       // 131,072
  float* ab     = (float*)(ws + 522960896);       // 2,048
  int*   cnt    = (int*)(ws + 522962944);         // 160,000
  int*   cursor = (int*)(ws + 523122944);         // 160,000
  int*   srcS   = (int*)(ws + 523282944);         // 2,560,000
  int*   dstS   = (int*)(ws + 525842944);         // 2,560,000
  int*   rank   = (int*)(ws + 528402944);         // 2,560,000 -> 530,962,944
  // ws_size >= 530,962,944 proven: R5 executed its SORTED path at this bound.

  prep_weights<<<144, 256, 0, stream>>>(W1, W2, w1t, w2t);
  cvt_vec<<<2500, 256, 0, stream>>>(h, hbf, 640000, 0);  // h -> bf16

  // counting sort of edges by dst (static across layers) + sorted bf16 e
  hipMemsetAsync(cnt, 0, 160000, stream);
  hist_dst<<<2500, 256, 0, stream>>>(dst, cnt);
  scan_hist<<<1, 1024, 0, stream>>>(cnt, cursor);
  rank_edges<<<2500, 256, 0, stream>>>(src, dst, cursor, srcS, dstS, rank);
  permute_e<<<10000, 256, 0, stream>>>(e, rank, ebfS);  // raw bf16, sorted order

  const int nblk = N_EDGES / 64;  // 10000
  for (int l = 0; l < 3; ++l) {
    hipMemsetAsync(stats, 0, 64 * 512 * 4, stream);
    gin_g1<<<nblk, 256, 0, stream>>>(hbf, ebfS, srcS,
                                     w1t + (size_t)l * 65536, xbuf, stats);
    if (l == 0)  // e := relu(e) for layers 1,2 (in place, packed bf16)
      relu_bf16_inplace<<<40000, 256, 0, stream>>>((unsigned int*)ebfS, 10240000);
    gin_bnstats<<<1, 256, 0, stream>>>(stats, gamma + l * 256, beta + l * 256, ab);
    float* hnext = (l < 2) ? h1 : out;
    hipMemsetAsync(hnext, 0, (size_t)N_NODES * 128 * 4, stream);
    gin_g2<<<nblk, 256, 0, stream>>>(xbuf, w2t + (size_t)l * 32768, ab,
                                     b2 + l * 128, dstS, hnext);
    if (l < 2) cvt_vec<<<2500, 256, 0, stream>>>(h1, hbf, 640000, 1);
  }
}

// Round 10
// 1234.670 us; speedup vs baseline: 1.6563x; 1.1731x over previous
//
#include <hip/hip_runtime.h>

typedef unsigned short u16;
typedef __attribute__((ext_vector_type(8))) short short8;
typedef __attribute__((ext_vector_type(4))) float f32x4;
typedef __attribute__((ext_vector_type(4))) unsigned int u32x4;

#define N_NODES 40000
#define N_EDGES 640000

// ---------- bf16 helpers (RNE) ----------
__device__ __forceinline__ u16 f2bf(float f) {
  unsigned int u = __builtin_bit_cast(unsigned int, f);
  u += 0x7FFFu + ((u >> 16) & 1u);
  return (u16)(u >> 16);
}
__device__ __forceinline__ float bf2f(u16 h) {
  unsigned int u = ((unsigned int)h) << 16;
  return __builtin_bit_cast(float, u);
}
// relu on 8 packed bf16 (sign-mask trick)
__device__ __forceinline__ short8 relu8(short8 s) {
  u32x4 w = __builtin_bit_cast(u32x4, s);
#pragma unroll
  for (int j = 0; j < 4; ++j) {
    unsigned int t = (w[j] >> 15) & 0x10001u;
    w[j] &= ~(t * 0xFFFFu);
  }
  return __builtin_bit_cast(short8, w);
}
// packed bf16 atomic add (gfx950 global_atomic_pk_add_bf16)
__device__ __forceinline__ void pk_atomic_add_bf16(u16* p, float c0, float c1) {
  unsigned int pk = (unsigned int)f2bf(c0) | ((unsigned int)f2bf(c1) << 16);
  asm volatile("global_atomic_pk_add_bf16 %0, %1, off" :: "v"(p), "v"(pk) : "memory");
}

// ---------- prep: W1/W2 f32 -> bf16, permuted into MFMA B-fragment order ----
// B frag for (ntile,ks): lane l holds B[k=ks*32+(l>>4)*8+j][n=ntile*16+(l&15)]
__global__ void prep_weights(const float* __restrict__ W1,
                             const float* __restrict__ W2,
                             u16* __restrict__ w1t, u16* __restrict__ w2t) {
  int gid = blockIdx.x * 256 + threadIdx.x;
  if (gid < 3 * 16 * 8 * 64) {            // W1: 3 layers x 16 ntiles x 8 ks x 64 lanes
    int l = gid >> 13;
    int rem = gid & 8191;
    int ntg = rem >> 9;
    int ks = (rem >> 6) & 7;
    int lane = rem & 63;
    int n = ntg * 16 + (lane & 15);
    int k0 = ks * 32 + (lane >> 4) * 8;
    const float* s = W1 + l * 65536 + n * 256 + k0;
    u16* d = w1t + (size_t)gid * 8;
#pragma unroll
    for (int j = 0; j < 8; ++j) d[j] = f2bf(s[j]);
  } else if (gid < 3 * 16 * 8 * 64 + 3 * 8 * 8 * 64) {  // W2: 8 ntiles
    int g = gid - 3 * 16 * 8 * 64;
    int l = g >> 12;
    int rem = g & 4095;
    int ntg = rem >> 9;
    int ks = (rem >> 6) & 7;
    int lane = rem & 63;
    int n = ntg * 16 + (lane & 15);
    int k0 = ks * 32 + (lane >> 4) * 8;
    const float* s = W2 + l * 32768 + n * 256 + k0;
    u16* d = w2t + (size_t)g * 8;
#pragma unroll
    for (int j = 0; j < 8; ++j) d[j] = f2bf(s[j]);
  }
}

// ---------- f32 -> bf16, vectorized x8 (initial h only) ----------
__global__ void cvt_vec(const float* __restrict__ in, u16* __restrict__ out,
                        int n8) {
  int i = blockIdx.x * 256 + threadIdx.x;
  if (i >= n8) return;
  const float4* p = reinterpret_cast<const float4*>(in) + (size_t)i * 2;
  float4 a = p[0], b = p[1];
  short8 v;
  v[0] = (short)f2bf(a.x); v[1] = (short)f2bf(a.y);
  v[2] = (short)f2bf(a.z); v[3] = (short)f2bf(a.w);
  v[4] = (short)f2bf(b.x); v[5] = (short)f2bf(b.y);
  v[6] = (short)f2bf(b.z); v[7] = (short)f2bf(b.w);
  *reinterpret_cast<short8*>(out + (size_t)i * 8) = v;
}

// ---------- counting sort of edges by dst ----------
__global__ void hist_dst(const int* __restrict__ dst, int* __restrict__ cnt) {
  int e = blockIdx.x * 256 + threadIdx.x;
  if (e < N_EDGES) atomicAdd(&cnt[dst[e]], 1);
}

__global__ void scan_hist(const int* __restrict__ cnt, int* __restrict__ cursor) {
  __shared__ int ls[1024];
  const int tid = threadIdx.x;  // 1024 threads, 40 nodes each
  const int b = tid * 40;
  const int lim = (b < N_NODES) ? ((N_NODES - b < 40) ? (N_NODES - b) : 40) : 0;
  int s = 0;
  for (int j = 0; j < lim; ++j) s += cnt[b + j];
  ls[tid] = s;
  __syncthreads();
  for (int off = 1; off < 1024; off <<= 1) {
    int v = (tid >= off) ? ls[tid - off] : 0;
    __syncthreads();
    ls[tid] += v;
    __syncthreads();
  }
  int run = (tid == 0) ? 0 : ls[tid - 1];
  for (int j = 0; j < lim; ++j) {
    cursor[b + j] = run;
    run += cnt[b + j];
  }
}

__global__ void rank_edges(const int* __restrict__ src, const int* __restrict__ dst,
                           int* __restrict__ cursor, int* __restrict__ srcS,
                           int* __restrict__ dstS, int* __restrict__ rank) {
  int e = blockIdx.x * 256 + threadIdx.x;
  if (e >= N_EDGES) return;
  int d = dst[e];
  int r = atomicAdd(&cursor[d], 1);
  rank[e] = r;
  srcS[r] = src[e];
  dstS[r] = d;
}

// ---------- permute e into sorted slot order, f32 -> bf16 (raw, no relu) ----
__global__ void permute_e(const float* __restrict__ e, const int* __restrict__ rank,
                          u16* __restrict__ ebfS) {
  int t = blockIdx.x * 256 + threadIdx.x;
  int row = t >> 2;
  int part = t & 3;  // 32-float chunk of the row
  if (row >= N_EDGES) return;
  const float4* p = reinterpret_cast<const float4*>(e + (size_t)row * 128 + part * 32);
  u16* dp = ebfS + (size_t)rank[row] * 128 + part * 32;
#pragma unroll
  for (int j = 0; j < 4; ++j) {
    float4 a = p[j * 2], b = p[j * 2 + 1];
    short8 v;
    v[0] = (short)f2bf(a.x); v[1] = (short)f2bf(a.y);
    v[2] = (short)f2bf(a.z); v[3] = (short)f2bf(a.w);
    v[4] = (short)f2bf(b.x); v[5] = (short)f2bf(b.y);
    v[6] = (short)f2bf(b.z); v[7] = (short)f2bf(b.w);
    *(short8*)(dp + j * 8) = v;
  }
}

// ---------- ladder building blocks ----------
#define LOAD_B4(SET, KS) { _Pragma("unroll") \
  for (int nt = 0; nt < 4; ++nt) \
    SET[nt] = *(const short8*)(wbase + ((nt * 8 + (KS)) * 64 + lane) * 8); }
#define LOAD_A_LDS(ARR, SET, KS) { _Pragma("unroll") \
  for (int mt = 0; mt < 4; ++mt) \
    SET[mt] = *(const short8*)&ARR[(KS)][mt * 16 + lrow][lk * 8]; }
#define MFMA4(ACC, A, B) { _Pragma("unroll") \
  for (int nt = 0; nt < 4; ++nt) { _Pragma("unroll") \
    for (int mt = 0; mt < 4; ++mt) \
      ACC[mt][nt] = __builtin_amdgcn_mfma_f32_16x16x32_bf16(A[mt], B[nt], ACC[mt][nt], 0, 0, 0); } }

// ---------- g1: x = concat(h[srcS], e)@W1^T ; x-write + col stats ----------
// A-tile staged depth-8 (R9-proven). RELU_E folds e:=relu(e) for layers 1,2
// at read time (ebfS stays raw; relu is idempotent).
template <int RELU_E>
__global__ __launch_bounds__(256) void gin_g1(
    const u16* __restrict__ hbf, const u16* __restrict__ ebf,
    const int* __restrict__ srcS, const u16* __restrict__ w1t,
    u16* __restrict__ xout, float* __restrict__ stats) {
  __shared__ u16 sA[8][64][36];  // 36,864 B
  const int tid = threadIdx.x;
  const long e0 = (long)blockIdx.x * 64;
  const int wid = tid >> 6, lane = tid & 63;
  const int lrow = lane & 15, lk = lane >> 4;

  // ---- stage: thread -> (row = tid>>2, chunk c2 = tid&3), one chunk per ks
  {
    const int row = tid >> 2, c2 = tid & 3;
    const int sr = srcS[e0 + row];
    const u16* hrow = hbf + (size_t)sr * 128 + c2 * 8;
    const u16* erow = ebf + (size_t)(e0 + row) * 128 + c2 * 8;
    short8 t0 = *(const short8*)(hrow + 0);
    short8 t1 = *(const short8*)(hrow + 32);
    short8 t2 = *(const short8*)(hrow + 64);
    short8 t3 = *(const short8*)(hrow + 96);
    short8 t4 = *(const short8*)(erow + 0);
    short8 t5 = *(const short8*)(erow + 32);
    short8 t6 = *(const short8*)(erow + 64);
    short8 t7 = *(const short8*)(erow + 96);
    if (RELU_E) { t4 = relu8(t4); t5 = relu8(t5); t6 = relu8(t6); t7 = relu8(t7); }
    *(short8*)&sA[0][row][c2 * 8] = t0;
    *(short8*)&sA[1][row][c2 * 8] = t1;
    *(short8*)&sA[2][row][c2 * 8] = t2;
    *(short8*)&sA[3][row][c2 * 8] = t3;
    *(short8*)&sA[4][row][c2 * 8] = t4;
    *(short8*)&sA[5][row][c2 * 8] = t5;
    *(short8*)&sA[6][row][c2 * 8] = t6;
    *(short8*)&sA[7][row][c2 * 8] = t7;
  }
  __syncthreads();

  // ---- K-ladder: A from LDS, B ping-pong from L2
  f32x4 acc[4][4] = {};
  const u16* wbase = w1t + (size_t)wid * 16384;
  {
    short8 a0[4], a1[4], b0[4], b1[4];
    LOAD_A_LDS(sA, a0, 0) LOAD_B4(b0, 0)
    LOAD_A_LDS(sA, a1, 1) LOAD_B4(b1, 1)
    MFMA4(acc, a0, b0)
    LOAD_A_LDS(sA, a0, 2) LOAD_B4(b0, 2)
    MFMA4(acc, a1, b1)
    LOAD_A_LDS(sA, a1, 3) LOAD_B4(b1, 3)
    MFMA4(acc, a0, b0)
    LOAD_A_LDS(sA, a0, 4) LOAD_B4(b0, 4)
    MFMA4(acc, a1, b1)
    LOAD_A_LDS(sA, a1, 5) LOAD_B4(b1, 5)
    MFMA4(acc, a0, b0)
    LOAD_A_LDS(sA, a0, 6) LOAD_B4(b0, 6)
    MFMA4(acc, a1, b1)
    LOAD_A_LDS(sA, a1, 7) LOAD_B4(b1, 7)
    MFMA4(acc, a0, b0)
    MFMA4(acc, a1, b1)
  }

  // ---- epilogue: direct x stores + col sum/sumsq partials
  float* statp = stats + (blockIdx.x & 63) * 512;
#pragma unroll
  for (int nt = 0; nt < 4; ++nt) {
    const int col = wid * 64 + nt * 16 + lrow;
    float sm = 0.f, sq = 0.f;
#pragma unroll
    for (int mt = 0; mt < 4; ++mt) {
#pragma unroll
      for (int i = 0; i < 4; ++i) {
        float v = acc[mt][nt][i];
        const long row = e0 + mt * 16 + lk * 4 + i;
        xout[(size_t)row * 256 + col] = f2bf(v);
        sm += v; sq += v * v;
      }
    }
    sm += __shfl_xor(sm, 16); sq += __shfl_xor(sq, 16);
    sm += __shfl_xor(sm, 32); sq += __shfl_xor(sq, 32);
    if (lk == 0) {
      atomicAdd(statp + col, sm);
      atomicAdd(statp + 256 + col, sq);
    }
  }
}

// ---------- BN finalize: a = gamma*rsqrt(var+eps), b = beta - mu*a ----------
__global__ void gin_bnstats(const float* __restrict__ stats,
                            const float* __restrict__ gamma,
                            const float* __restrict__ beta,
                            float* __restrict__ ab) {
  int c = threadIdx.x;  // 256 threads
  float sm = 0.f, sq = 0.f;
  for (int i = 0; i < 64; ++i) {
    sm += stats[i * 512 + c];
    sq += stats[i * 512 + 256 + c];
  }
  const float inv = 1.0f / (float)N_EDGES;
  float mu = sm * inv;
  float var = fmaxf(sq * inv - mu * mu, 0.f);
  float a = gamma[c] * rsqrtf(var + 1e-5f);
  ab[c] = a;
  ab[256 + c] = beta[c] - mu * a;
}

// ---------- scat: Y[dst] += relu(a*x+b)  (segment-sum BEFORE GEMM2) --------
// Thread = (col pair, row half). dst uniform per wave -> no divergence;
// pk-bf16 atomics, 256B-coalesced per wave, carries in f32.
__global__ __launch_bounds__(256) void gin_scat(
    const u16* __restrict__ xin, const float* __restrict__ ab,
    const int* __restrict__ dstS, u16* __restrict__ Y) {
  const int tid = threadIdx.x;
  const long e0 = (long)blockIdx.x * 64;
  const int cp = tid & 127;          // column pair 0..127
  const int half = tid >> 7;         // 0 -> rows 0..31, 1 -> rows 32..63
  const int col = cp * 2;
  const int r0 = half * 32;
  const float a0 = ab[col], a1 = ab[col + 1];
  const float b0 = ab[256 + col], b1 = ab[256 + col + 1];
  float c0 = 0.f, c1 = 0.f;
  int cur = dstS[e0 + r0];
#pragma unroll 8
  for (int r = r0; r < r0 + 32; ++r) {
    unsigned int u = *(const unsigned int*)(xin + (size_t)(e0 + r) * 256 + col);
    float y0 = fmaxf(bf2f((u16)(u & 0xFFFFu)) * a0 + b0, 0.f);
    float y1 = fmaxf(bf2f((u16)(u >> 16)) * a1 + b1, 0.f);
    int d = dstS[e0 + r];
    if (d != cur) {
      pk_atomic_add_bf16(Y + (size_t)cur * 256 + col, c0, c1);
      c0 = 0.f; c1 = 0.f; cur = d;
    }
    c0 += y0; c1 += y1;
  }
  pk_atomic_add_bf16(Y + (size_t)cur * 256 + col, c0, c1);
}

// ---------- nodegemm: h = Y @ W2^T + deg*b2 ; relu+bf16 (l<2) or f32 out ----
template <int LAST>
__global__ __launch_bounds__(256) void gin_nodegemm(
    const u16* __restrict__ Y, const u16* __restrict__ w2t,
    const float* __restrict__ b2, const int* __restrict__ cnt,
    float* __restrict__ outf, u16* __restrict__ hbf) {
  const int tid = threadIdx.x;
  const long n0 = (long)blockIdx.x * 64;
  const int wid = tid >> 6, lane = tid & 63;
  const int lrow = lane & 15, lk = lane >> 4;
  f32x4 acc[4][2] = {};
  const u16* wb2 = w2t + (size_t)wid * 8192;
  for (int ks = 0; ks < 8; ++ks) {
    short8 af[4];
#pragma unroll
    for (int mt = 0; mt < 4; ++mt)
      af[mt] = *(const short8*)(Y + (size_t)(n0 + mt * 16 + lrow) * 256 +
                                ks * 32 + lk * 8);
#pragma unroll
    for (int nt = 0; nt < 2; ++nt) {
      short8 bf = *(const short8*)(wb2 + ((nt * 8 + ks) * 64 + lane) * 8);
#pragma unroll
      for (int mt = 0; mt < 4; ++mt)
        acc[mt][nt] =
            __builtin_amdgcn_mfma_f32_16x16x32_bf16(af[mt], bf, acc[mt][nt], 0, 0, 0);
    }
  }
  float bb[2];
#pragma unroll
  for (int nt = 0; nt < 2; ++nt) bb[nt] = b2[wid * 32 + nt * 16 + lrow];
#pragma unroll
  for (int mt = 0; mt < 4; ++mt) {
#pragma unroll
    for (int i = 0; i < 4; ++i) {
      const long node = n0 + mt * 16 + lk * 4 + i;
      const float dg = (float)cnt[node];
#pragma unroll
      for (int nt = 0; nt < 2; ++nt) {
        const int col = wid * 32 + nt * 16 + lrow;
        float v = acc[mt][nt][i] + dg * bb[nt];
        if (LAST) outf[node * 128 + col] = v;
        else      hbf[node * 128 + col] = f2bf(fmaxf(v, 0.f));
      }
    }
  }
}

// ---------- launch ----------
extern "C" void kernel_launch(void* const* d_in, const int* in_sizes, int n_in,
                              void* d_out, int out_size, void* d_ws, size_t ws_size,
                              hipStream_t stream) {
  const float* h     = (const float*)d_in[0];
  const float* e     = (const float*)d_in[1];
  const float* W1    = (const float*)d_in[2];
  // d_in[3] = b1: cancels exactly in BatchNorm -> unused
  const float* gamma = (const float*)d_in[4];
  const float* beta  = (const float*)d_in[5];
  const float* W2    = (const float*)d_in[6];
  const float* b2    = (const float*)d_in[7];
  const int* src     = (const int*)d_in[8];
  const int* dst     = (const int*)d_in[9];
  float* out = (float*)d_out;

  char* ws = (char*)d_ws;
  u16*   xbuf   = (u16*)(ws);                     // 327,680,000
  u16*   ebfS   = (u16*)(ws + 327680000);         // 163,840,000 (raw, immutable)
  u16*   hbf    = (u16*)(ws + 491520000);         // 10,240,000
  u16*   Y      = (u16*)(ws + 501760000);         // 20,480,000 (bf16 node acc)
  u16*   w1t    = (u16*)(ws + 522240000);         // 393,216
  u16*   w2t    = (u16*)(ws + 522633216);         // 196,608
  float* stats  = (float*)(ws + 522829824);       // 131,072
  float* ab     = (float*)(ws + 522960896);       // 2,048
  int*   cnt    = (int*)(ws + 522962944);         // 160,000
  int*   cursor = (int*)(ws + 523122944);         // 160,000
  int*   srcS   = (int*)(ws + 523282944);         // 2,560,000
  int*   dstS   = (int*)(ws + 525842944);         // 2,560,000
  int*   rank   = (int*)(ws + 528402944);         // 2,560,000 -> 530,962,944
  // total identical to R9's proven workspace bound.

  prep_weights<<<144, 256, 0, stream>>>(W1, W2, w1t, w2t);
  cvt_vec<<<2500, 256, 0, stream>>>(h, hbf, 640000);  // h -> bf16

  // counting sort of edges by dst (static across layers) + sorted bf16 e
  hipMemsetAsync(cnt, 0, 160000, stream);
  hist_dst<<<2500, 256, 0, stream>>>(dst, cnt);
  scan_hist<<<1, 1024, 0, stream>>>(cnt, cursor);
  rank_edges<<<2500, 256, 0, stream>>>(src, dst, cursor, srcS, dstS, rank);
  permute_e<<<10000, 256, 0, stream>>>(e, rank, ebfS);  // raw bf16, sorted order

  const int nblk = N_EDGES / 64;  // 10000
  for (int l = 0; l < 3; ++l) {
    hipMemsetAsync(stats, 0, 64 * 512 * 4, stream);
    if (l == 0)
      gin_g1<0><<<nblk, 256, 0, stream>>>(hbf, ebfS, srcS, w1t, xbuf, stats);
    else
      gin_g1<1><<<nblk, 256, 0, stream>>>(hbf, ebfS, srcS,
                                          w1t + (size_t)l * 65536, xbuf, stats);
    gin_bnstats<<<1, 256, 0, stream>>>(stats, gamma + l * 256, beta + l * 256, ab);
    hipMemsetAsync(Y, 0, 20480000, stream);
    gin_scat<<<nblk, 256, 0, stream>>>(xbuf, ab, dstS, Y);
    if (l < 2)
      gin_nodegemm<0><<<625, 256, 0, stream>>>(Y, w2t + (size_t)l * 32768,
                                               b2 + l * 128, cnt, nullptr, hbf);
    else
      gin_nodegemm<1><<<625, 256, 0, stream>>>(Y, w2t + (size_t)l * 32768,
                                               b2 + l * 128, cnt, out, nullptr);
  }
}